// Round 10
// baseline (65.457 us; speedup 1.0000x reference)
//
#include <hip/hip_runtime.h>
#include <math.h>

#define Cc 512
#define Pp 1024
#define NROW 25088      // B*N = 8*3136
#define BM 128          // rows per block
#define BNP 128         // centroid cols per block (8 pblocks)
#define BK 32           // K tile (16 K-steps)
#define NMB 196         // real mblocks = 25088/128
#define NMB_PAD 200     // padded so mblocks group 8-per-XCD
#define BIAS 4096.f     // makes v = cn+BIAS-2dot strictly positive for packing

typedef short  bf16x8 __attribute__((ext_vector_type(8)));   // 8 bf16 = 4 VGPR
typedef float  f32x4  __attribute__((ext_vector_type(4)));
typedef unsigned short u16x8 __attribute__((ext_vector_type(8)));
typedef unsigned short u16x4 __attribute__((ext_vector_type(4)));

__device__ __forceinline__ unsigned short bf16_rne(float f) {
    unsigned int u = __float_as_uint(f);
    return (unsigned short)((u + 0x7fffu + ((u >> 16) & 1u)) >> 16);
}

// branch-free sorted insert (float), for cross-pblock merges
#define TOP3_INSERT(t0, t1, t2, v)                                  \
    do {                                                            \
        float _n0 = fminf((t0), (v));                               \
        float _h0 = fmaxf((t0), (v));                               \
        float _n1 = fminf((t1), _h0);                               \
        float _h1 = fmaxf((t1), _h0);                               \
        float _n2 = fminf((t2), _h1);                               \
        (t0) = _n0; (t1) = _n1; (t2) = _n2;                         \
    } while (0)

// branch-free sorted insert (packed u32: high-24 float bits | 8-bit col id)
#define TOP3_INS_U32(t0, t1, t2, v)                                 \
    do {                                                            \
        unsigned int _n0 = min((t0), (v));                          \
        unsigned int _h0 = max((t0), (v));                          \
        unsigned int _n1 = min((t1), _h0);                          \
        unsigned int _h1 = max((t1), _h0);                          \
        unsigned int _n2 = min((t2), _h1);                          \
        (t0) = _n0; (t1) = _n1; (t2) = _n2;                         \
    } while (0)

#define GLOAD_LDS16(gp, lp)                                             \
    __builtin_amdgcn_global_load_lds(                                   \
        (const __attribute__((address_space(1))) void*)(const void*)(gp),\
        (__attribute__((address_space(3))) void*)(void*)(lp), 16, 0, 0)

// ---------------------------------------------------------------------------
// Centroid conv: fp32 -> bf16 (RNE) row-major + squared norm. One wave/row.
// ---------------------------------------------------------------------------
__global__ __launch_bounds__(256) void conv_norm_kernel(
        const float* __restrict__ src, unsigned short* __restrict__ dst,
        float* __restrict__ nrm) {
    int wid  = blockIdx.x * 4 + (threadIdx.x >> 6);
    int lane = threadIdx.x & 63;
    const float4* r = (const float4*)(src + (size_t)wid * Cc);
    float4 a = r[lane * 2];
    float4 b = r[lane * 2 + 1];
    u16x8 o;
    o[0] = bf16_rne(a.x); o[1] = bf16_rne(a.y); o[2] = bf16_rne(a.z); o[3] = bf16_rne(a.w);
    o[4] = bf16_rne(b.x); o[5] = bf16_rne(b.y); o[6] = bf16_rne(b.z); o[7] = bf16_rne(b.w);
    *(u16x8*)(dst + (size_t)wid * Cc + lane * 8) = o;
    float s = a.x*a.x + a.y*a.y + a.z*a.z + a.w*a.w
            + b.x*b.x + b.y*b.y + b.z*b.z + b.w*b.w;
    #pragma unroll
    for (int m = 1; m < 64; m <<= 1) s += __shfl_xor(s, m);
    if (lane == 0) nrm[wid] = s;
}

// ---------------------------------------------------------------------------
// FUSED main: reads fp32 embeds directly. Per K-step (BK=32):
//   issue A(t+1) fp32->regs (4x coalesced float4), issue B(t+2) gload_lds
//   (3-ring), ds_read+16 MFMA on step t, vmcnt(2) [A landed, B(t+2) in
//   flight], convert A RNE + sumsq (fnorm for free) + swizzled ds_write
//   into A-ring(t+1), lgkmcnt(0), barrier. Never vmcnt(0) until t=14.
// XOR-swizzled LDS both-sides; XCD-grouped P-split; swapped-operand MFMA
// (cents lane-local in C) + packed-u32 top-3 epilogue.
// Grid: 1600 blocks (200 padded mblocks x 8 pblocks), 256 thr = 4 waves 2x2.
// acc[mc][nr]: cent = p0+wn*64+mc*16+g*4+reg ; row = row0+wm*64+nr*16+q
// ---------------------------------------------------------------------------
__global__ __launch_bounds__(256, 3) void mfma_topk_kernel(
        const float* __restrict__ E, const unsigned short* __restrict__ Cb,
        const float* __restrict__ cnorm, float* __restrict__ wsTop,
        float* __restrict__ fnorm) {
    const int xcd = blockIdx.x & 7;
    const int t8  = blockIdx.x >> 3;          // 0..199
    const int mblock = ((t8 >> 3) << 3) | xcd;
    const int pblock = t8 & 7;
    if (mblock >= NMB) return;                // uniform early-exit

    __shared__ unsigned short Alds[2][BM * BK];   // 2 x 8 KB
    __shared__ unsigned short Blds[3][BNP * BK];  // 3 x 8 KB

    const int tid  = threadIdx.x;
    const int lane = tid & 63;
    const int w    = tid >> 6;
    const int wm   = w >> 1;       // 0..1 row half
    const int wn   = w & 1;        // 0..1 cent half
    const int g    = lane >> 4;    // 0..3
    const int q    = lane & 15;    // 0..15
    const int mq   = (q ^ (q >> 2)) & 3;   // reader swizzle (wave-uniform per frag)
    const int row0 = mblock * BM;
    const int p0   = pblock * BNP;

    f32x4 acc[4][4];               // [mc][nr]
    #pragma unroll
    for (int mc = 0; mc < 4; ++mc)
        #pragma unroll
        for (int nr = 0; nr < 4; ++nr) acc[mc][nr] = (f32x4){0.f, 0.f, 0.f, 0.f};

    // ---- A path: fp32 global -> regs -> convert -> swizzled ds_write ----
    // chunk c = tid + it*256 (1024 float4/step): row = c>>3, pos = c&7
    const int arow = tid >> 3, apos = tid & 7;
    const int aslot = apos >> 1, ahalf = apos & 1;
    const float* Ag = E + (size_t)(row0 + arow) * Cc + apos * 4;
    float4 ra[4];
    float sums[4] = {0.f, 0.f, 0.f, 0.f};

    auto LOAD_A = [&](int kk) {
        #pragma unroll
        for (int it = 0; it < 4; ++it)
            ra[it] = *(const float4*)(Ag + it * (32 * Cc) + kk);
    };
    auto WRITE_A = [&](int buf) {
        #pragma unroll
        for (int it = 0; it < 4; ++it) {
            int row = arow + 32 * it;
            int sw  = aslot ^ ((row ^ (row >> 2)) & 3);
            u16x4 o;
            o[0] = bf16_rne(ra[it].x); o[1] = bf16_rne(ra[it].y);
            o[2] = bf16_rne(ra[it].z); o[3] = bf16_rne(ra[it].w);
            sums[it] = fmaf(ra[it].x, ra[it].x, sums[it]);
            sums[it] = fmaf(ra[it].y, ra[it].y, sums[it]);
            sums[it] = fmaf(ra[it].z, ra[it].z, sums[it]);
            sums[it] = fmaf(ra[it].w, ra[it].w, sums[it]);
            *(u16x4*)((char*)Alds[buf] + row * 64 + sw * 16 + ahalf * 8) = o;
        }
    };
    // ---- B path: gload_lds, source pre-swizzled (involution) ----
    auto STAGE_B = [&](int buf, int kk) {
        #pragma unroll
        for (int it = 0; it < 2; ++it) {
            int c = tid + it * 256;
            int row = c >> 2;
            int sg  = (c & 3) ^ ((row ^ (row >> 2)) & 3);
            GLOAD_LDS16(Cb + (size_t)(p0 + row) * Cc + kk + sg * 8,
                        (char*)Blds[buf] + c * 16);
        }
    };

    // prologue: A(0) regs + B(0),B(1) DMA; finish A(0)+B(0), B(1) stays out
    LOAD_A(0);
    STAGE_B(0, 0);
    STAGE_B(1, BK);
    asm volatile("s_waitcnt vmcnt(2)" ::: "memory");   // A0(4)+B0(2) done
    WRITE_A(0);
    asm volatile("s_waitcnt lgkmcnt(0)" ::: "memory");
    __builtin_amdgcn_s_barrier();

    int bB = 2;                       // next B ring slot to stage
    for (int t = 0; t < 16; ++t) {
        if (t < 15) LOAD_A((t + 1) * BK);
        if (t < 14) { STAGE_B(bB, (t + 2) * BK); bB = (bB == 2) ? 0 : bB + 1; }

        const char* As = (const char*)Alds[t & 1];
        const char* Bs = (const char*)Blds[t % 3];
        const int slot = (g ^ mq) * 16;
        bf16x8 bc[4], ar[4];
        #pragma unroll
        for (int mc = 0; mc < 4; ++mc)
            bc[mc] = *(const bf16x8*)(Bs + (wn * 64 + mc * 16 + q) * 64 + slot);
        #pragma unroll
        for (int nr = 0; nr < 4; ++nr)
            ar[nr] = *(const bf16x8*)(As + (wm * 64 + nr * 16 + q) * 64 + slot);
        __builtin_amdgcn_s_setprio(1);
        #pragma unroll
        for (int mc = 0; mc < 4; ++mc)
            #pragma unroll
            for (int nr = 0; nr < 4; ++nr)
                acc[mc][nr] = __builtin_amdgcn_mfma_f32_16x16x32_bf16(
                    bc[mc], ar[nr], acc[mc][nr], 0, 0, 0);
        __builtin_amdgcn_s_setprio(0);

        if (t < 15) {
            // A(t+1) raw loads are older than B(t+2)'s 2 DMA ops
            if (t < 14) asm volatile("s_waitcnt vmcnt(2)" ::: "memory");
            else        asm volatile("s_waitcnt vmcnt(0)" ::: "memory");
            WRITE_A((t + 1) & 1);
            asm volatile("s_waitcnt lgkmcnt(0)" ::: "memory");
            __builtin_amdgcn_s_barrier();
        }
    }

    // ---- fnorm: pblock 0 writes per-row sum of squares (fp32-exact) ----
    if (pblock == 0) {
        #pragma unroll
        for (int m = 1; m <= 4; m <<= 1)
            #pragma unroll
            for (int it = 0; it < 4; ++it)
                sums[it] += __shfl_xor(sums[it], m);
        if (apos == 0)
            #pragma unroll
            for (int it = 0; it < 4; ++it)
                fnorm[row0 + arow + 32 * it] = sums[it];
    }

    // ---- epilogue: cents lane-local; top-3 per row over 64 cents/wave ----
    float cnb[4][4];
    #pragma unroll
    for (int mc = 0; mc < 4; ++mc)
        #pragma unroll
        for (int reg = 0; reg < 4; ++reg)
            cnb[mc][reg] = cnorm[p0 + wn * 64 + mc * 16 + g * 4 + reg] + BIAS;

    __syncthreads();               // all ds_reads of Alds done before alias
    float* tops = (float*)Alds;    // alias: [2][BM][3] floats (3 KB)

    #pragma unroll
    for (int nr = 0; nr < 4; ++nr) {
        unsigned int u0 = 0xFFFFFFFFu, u1 = 0xFFFFFFFFu, u2 = 0xFFFFFFFFu;
        #pragma unroll
        for (int mc = 0; mc < 4; ++mc)
            #pragma unroll
            for (int reg = 0; reg < 4; ++reg) {
                float v = fmaf(-2.f, acc[mc][nr][reg], cnb[mc][reg]);  // > 0
                unsigned int cl = (unsigned int)(wn * 64 + mc * 16 + g * 4 + reg);
                unsigned int u = (__float_as_uint(v) & 0xFFFFFF00u) | cl;
                TOP3_INS_U32(u0, u1, u2, u);
            }
        #pragma unroll
        for (int mask = 16; mask <= 32; mask <<= 1) {
            unsigned int o0 = (unsigned int)__shfl_xor((int)u0, mask);
            unsigned int o1 = (unsigned int)__shfl_xor((int)u1, mask);
            unsigned int o2 = (unsigned int)__shfl_xor((int)u2, mask);
            TOP3_INS_U32(u0, u1, u2, o0);
            TOP3_INS_U32(u0, u1, u2, o1);
            TOP3_INS_U32(u0, u1, u2, o2);
        }
        if (g == 0) {
            int rl = wm * 64 + nr * 16 + q;
            float* d = tops + ((size_t)wn * BM + rl) * 3;
            d[0] = __uint_as_float(u0 & 0xFFFFFF00u) - BIAS;
            d[1] = __uint_as_float(u1 & 0xFFFFFF00u) - BIAS;
            d[2] = __uint_as_float(u2 & 0xFFFFFF00u) - BIAS;
        }
    }
    __syncthreads();

    if (tid < BM) {
        const float* p = tops + (size_t)tid * 3;
        float a0v = p[0], a1v = p[1], a2v = p[2];
        const float* p1 = tops + ((size_t)BM + tid) * 3;
        TOP3_INSERT(a0v, a1v, a2v, p1[0]);
        TOP3_INSERT(a0v, a1v, a2v, p1[1]);
        TOP3_INSERT(a0v, a1v, a2v, p1[2]);
        float* dst = wsTop + (size_t)(row0 + tid) * 24 + pblock * 3;
        dst[0] = a0v; dst[1] = a1v; dst[2] = a2v;
    }
}

// ---------------------------------------------------------------------------
// Final merge: fold 8 pblocks' top3, add row norm, sqrt + softmin, store.
// ---------------------------------------------------------------------------
__global__ __launch_bounds__(256) void merge_kernel(
        const float* __restrict__ wsTop, const float* __restrict__ fnorm,
        float* __restrict__ out) {
    int r = blockIdx.x * 256 + threadIdx.x;      // 25088 = 98*256 exact
    const float* p = wsTop + (size_t)r * 24;
    float t0 = p[0], t1 = p[1], t2 = p[2];
    #pragma unroll
    for (int pb = 1; pb < 8; ++pb) {
        TOP3_INSERT(t0, t1, t2, p[pb * 3 + 0]);
        TOP3_INSERT(t0, t1, t2, p[pb * 3 + 1]);
        TOP3_INSERT(t0, t1, t2, p[pb * 3 + 2]);
    }
    float fn = fnorm[r];
    float d0 = sqrtf(fmaxf(fn + t0, 0.f));
    float d1 = sqrtf(fmaxf(fn + t1, 0.f));
    float d2 = sqrtf(fmaxf(fn + t2, 0.f));
    float w0 = 1.f / (1.f + __expf(d0 - d1) + __expf(d0 - d2));
    out[r] = w0 * d0;
}

extern "C" void kernel_launch(void* const* d_in, const int* in_sizes, int n_in,
                              void* d_out, int out_size, void* d_ws, size_t ws_size,
                              hipStream_t stream) {
    (void)in_sizes; (void)n_in; (void)out_size; (void)ws_size;
    const float* embeds    = (const float*)d_in[0];   // [8,3136,512] fp32
    const float* centroids = (const float*)d_in[1];   // [1024,512]  fp32
    float* out = (float*)d_out;

    // ws layout (bytes):
    //   cnorm  @ 0         (4 KB)
    //   fnorm  @ 4096      (100,352 B)
    //   wsTop  @ 104448    (25088*8*3*4 = 2,408,448 B)  [row][pblock][3]
    //   Cb     @ 28203008  (1,048,576 B bf16 row-major)
    char* ws = (char*)d_ws;
    float*          cnorm = (float*)(ws);
    float*          fnorm = (float*)(ws + 4096);
    float*          wsTop = (float*)(ws + 104448);
    unsigned short* Cb    = (unsigned short*)(ws + 28203008);

    conv_norm_kernel<<<Pp / 4, 256, 0, stream>>>(centroids, Cb, cnorm);
    mfma_topk_kernel<<<NMB_PAD * 8, 256, 0, stream>>>(embeds, Cb, cnorm, wsTop, fnorm);
    merge_kernel<<<NROW / 256, 256, 0, stream>>>(wsTop, fnorm, out);
}

// Round 11
// 57.910 us; speedup vs baseline: 1.1303x; 1.1303x over previous
//
#include <hip/hip_runtime.h>
#include <math.h>

#define Cc 512
#define Pp 1024
#define NROW 25088      // B*N = 8*3136
#define BM 128          // rows per block
#define BNP 128         // centroid cols per block (8 pblocks)
#define NMB 196         // real mblocks = 25088/128
#define NMB_PAD 200     // padded so mblocks group 8-per-XCD
#define BIAS 4096.f     // makes v = cn+BIAS-2dot strictly positive for packing

typedef short  bf16x8 __attribute__((ext_vector_type(8)));   // 8 bf16 = 4 VGPR
typedef float  f32x4  __attribute__((ext_vector_type(4)));
typedef unsigned short u16x8 __attribute__((ext_vector_type(8)));
typedef unsigned short u16x4 __attribute__((ext_vector_type(4)));

__device__ __forceinline__ unsigned short bf16_rne(float f) {
    unsigned int u = __float_as_uint(f);
    return (unsigned short)((u + 0x7fffu + ((u >> 16) & 1u)) >> 16);
}

// branch-free sorted insert (float), for cross-pblock merges
#define TOP3_INSERT(t0, t1, t2, v)                                  \
    do {                                                            \
        float _n0 = fminf((t0), (v));                               \
        float _h0 = fmaxf((t0), (v));                               \
        float _n1 = fminf((t1), _h0);                               \
        float _h1 = fmaxf((t1), _h0);                               \
        float _n2 = fminf((t2), _h1);                               \
        (t0) = _n0; (t1) = _n1; (t2) = _n2;                         \
    } while (0)

// branch-free sorted insert (packed u32: high-24 float bits | 8-bit col id)
#define TOP3_INS_U32(t0, t1, t2, v)                                 \
    do {                                                            \
        unsigned int _n0 = min((t0), (v));                          \
        unsigned int _h0 = max((t0), (v));                          \
        unsigned int _n1 = min((t1), _h0);                          \
        unsigned int _h1 = max((t1), _h0);                          \
        unsigned int _n2 = min((t2), _h1);                          \
        (t0) = _n0; (t1) = _n1; (t2) = _n2;                         \
    } while (0)

#define GLOAD_LDS16(gp, lp)                                             \
    __builtin_amdgcn_global_load_lds(                                   \
        (const __attribute__((address_space(1))) void*)(const void*)(gp),\
        (__attribute__((address_space(3))) void*)(void*)(lp), 16, 0, 0)

// ---------------------------------------------------------------------------
// Transpose-conv (proven in R9): fp32 -> bf16 RNE, re-tiled into MFMA
// fragment order, fused row squared-norm.
// Tile = 16 rows x 32 k = 64 chunks of 16B; chunk (g,q) at lane l = g*16+q.
// Tile id = rowblk_base + kt*ktstride + nrt, rowblk_base = rb + (rb>>lg)*(15<<lg)
//   A (embeds):    lg=3, ktstride=8   -> [mblock][kstep 16][nrtile 8][64*16B]
//   B (centroids): lg=6, ktstride=64  -> [kstep 16][ptile 64][64*16B]
// ---------------------------------------------------------------------------
__global__ __launch_bounds__(256) void tconv_kernel(
        const float* __restrict__ src, unsigned short* __restrict__ dst,
        float* __restrict__ nrm, int lg, int ktstride) {
    __shared__ unsigned short buf[32 * 512];   // 32 KB
    __shared__ float snorm[32 * 8];            // 1 KB

    const int t = threadIdx.x;
    const size_t R0 = (size_t)blockIdx.x * 32;

    #pragma unroll
    for (int p = 0; p < 16; ++p) {
        int idx = p * 1024 + t * 4;
        float4 v = *(const float4*)(src + R0 * Cc + idx);
        u16x4 o;
        o[0] = bf16_rne(v.x); o[1] = bf16_rne(v.y);
        o[2] = bf16_rne(v.z); o[3] = bf16_rne(v.w);
        *(u16x4*)&buf[idx] = o;
    }
    __syncthreads();

    const int w = t >> 6, g = (t >> 4) & 3, q = t & 15, l = t & 63;
    const int rb = (int)(R0 >> 4);
    const int rowblk_base = rb + (rb >> lg) * (15 << lg);
    float fns = 0.f;
    #pragma unroll
    for (int p = 0; p < 8; ++p) {
        int cg  = p * 4 + w;              // tile-local group 0..31
        int kt  = cg >> 1, nrt = cg & 1;
        int row = nrt * 16 + q;
        u16x8 ch = *(const u16x8*)&buf[row * 512 + kt * 32 + g * 8];
        #pragma unroll
        for (int i = 0; i < 8; ++i) {
            float x = __uint_as_float((unsigned int)(unsigned short)ch[i] << 16);
            fns = fmaf(x, x, fns);
        }
        size_t tile = (size_t)rowblk_base + (size_t)kt * ktstride + nrt;
        *(u16x8*)(dst + tile * 512 + l * 8) = ch;
    }
    snorm[((w & 1) * 16 + q) * 8 + (w >> 1) * 4 + g] = fns;
    __syncthreads();
    if (t < 32) {
        float s = 0.f;
        #pragma unroll
        for (int j = 0; j < 8; ++j) s += snorm[t * 8 + j];
        nrm[R0 + t] = s;
    }
}

// ---------------------------------------------------------------------------
// Main: split-pipe 128x128 MFMA tile. A fragments load DIRECT global->VGPR
// (fragment-tiled => one coalesced dwordx4/lane, L1/L2-hot; reg-dependency
// waits are compiler-counted -> no manual drain). B staged via gload_lds
// into a 3-slot fragment-ordered LDS ring (contiguous 1KB/wave reads =
// conflict-free, no swizzle); counted vmcnt(6) per step, never 0 until tail.
// Swapped-operand MFMA (cents lane-local in C) + packed-u32 top-3.
// Grid: 1600 blocks (200 padded mblocks x 8 pblocks), 256 thr = 4 waves 2x2.
// acc[mc][nr]: cent = p0+wn*64+mc*16+g*4+reg ; row = row0+wm*64+nr*16+q
// ---------------------------------------------------------------------------
__global__ __launch_bounds__(256, 3) void mfma_topk_kernel(
        const unsigned short* __restrict__ EbT, const unsigned short* __restrict__ CbT,
        const float* __restrict__ cnorm, float* __restrict__ wsTop) {
    const int xcd = blockIdx.x & 7;
    const int t8  = blockIdx.x >> 3;          // 0..199
    const int mblock = ((t8 >> 3) << 3) | xcd;
    const int pblock = t8 & 7;
    if (mblock >= NMB) return;                // uniform early-exit

    __shared__ unsigned short Blds[3][BNP * 32];  // 3 x 8 KB ring
    __shared__ float tops[2][BM][3];              // 3 KB

    const int tid  = threadIdx.x;
    const int lane = tid & 63;
    const int w    = tid >> 6;
    const int wm   = w >> 1;       // 0..1 row half
    const int wn   = w & 1;        // 0..1 cent half
    const int g    = lane >> 4;    // 0..3
    const int q    = lane & 15;    // 0..15
    const int row0 = mblock * BM;
    const int p0   = pblock * BNP;

    f32x4 acc[4][4];               // [mc][nr]
    #pragma unroll
    for (int mc = 0; mc < 4; ++mc)
        #pragma unroll
        for (int nr = 0; nr < 4; ++nr) acc[mc][nr] = (f32x4){0.f, 0.f, 0.f, 0.f};

    // A fragment base (u16): tile=512 u16, tiles [mblock][kt 16][nrt 8]
    const unsigned short* Ab = EbT + ((size_t)mblock * 128 + wm * 4) * 512 + lane * 8;
    // B k-step panel: tiles [kt 16][ptile 64]; block's 8 tiles contiguous
    const unsigned short* Bg = CbT + (size_t)pblock * 8 * 512;

    // stage B k-step kt into ring slot buf: 8 KB = 512 x 16B, 2 chunks/thread
    auto STAGE_B = [&](int buf, int kt) {
        const unsigned short* src = Bg + (size_t)kt * 32768;
        #pragma unroll
        for (int it = 0; it < 2; ++it) {
            int c = tid + it * 256;
            GLOAD_LDS16(src + c * 8, (char*)Blds[buf] + c * 16);
        }
    };

    bf16x8 af[2][4];
    STAGE_B(0, 0);
    #pragma unroll
    for (int nr = 0; nr < 4; ++nr) af[0][nr] = *(const bf16x8*)(Ab + nr * 512);
    STAGE_B(1, 1);
    // drain B(0): newer in flight = A(0) 4 + B(1) 2
    asm volatile("s_waitcnt vmcnt(6)" ::: "memory");
    __builtin_amdgcn_s_barrier();

    #pragma unroll
    for (int t = 0; t < 16; ++t) {
        const int cur = t & 1, nxt = cur ^ 1;
        if (t < 15) {
            #pragma unroll
            for (int nr = 0; nr < 4; ++nr)
                af[nxt][nr] = *(const bf16x8*)(Ab + (t + 1) * 4096 + nr * 512);
        }
        if (t < 14) STAGE_B((t + 2) % 3, t + 2);

        const char* Bs = (const char*)Blds[t % 3];
        bf16x8 bc[4];
        #pragma unroll
        for (int mc = 0; mc < 4; ++mc)
            bc[mc] = *(const bf16x8*)(Bs + (wn * 4 + mc) * 1024 + lane * 16);
        __builtin_amdgcn_s_setprio(1);
        #pragma unroll
        for (int mc = 0; mc < 4; ++mc)
            #pragma unroll
            for (int nr = 0; nr < 4; ++nr)
                acc[mc][nr] = __builtin_amdgcn_mfma_f32_16x16x32_bf16(
                    bc[mc], af[cur][nr], acc[mc][nr], 0, 0, 0);
        __builtin_amdgcn_s_setprio(0);

        if (t < 15) {
            // drain B(t+1); keep A(t+1) 4 + B(t+2) 2 in flight
            if (t < 14) asm volatile("s_waitcnt vmcnt(6)" ::: "memory");
            else        asm volatile("s_waitcnt vmcnt(4)" ::: "memory");
            __builtin_amdgcn_s_barrier();
        }
    }

    // ---- epilogue: cents lane-local; top-3 per row over 64 cents/wave ----
    float cnb[4][4];
    #pragma unroll
    for (int mc = 0; mc < 4; ++mc)
        #pragma unroll
        for (int reg = 0; reg < 4; ++reg)
            cnb[mc][reg] = cnorm[p0 + wn * 64 + mc * 16 + g * 4 + reg] + BIAS;

    #pragma unroll
    for (int nr = 0; nr < 4; ++nr) {
        unsigned int u0 = 0xFFFFFFFFu, u1 = 0xFFFFFFFFu, u2 = 0xFFFFFFFFu;
        #pragma unroll
        for (int mc = 0; mc < 4; ++mc)
            #pragma unroll
            for (int reg = 0; reg < 4; ++reg) {
                float v = fmaf(-2.f, acc[mc][nr][reg], cnb[mc][reg]);  // > 0
                unsigned int cl = (unsigned int)(wn * 64 + mc * 16 + g * 4 + reg);
                unsigned int u = (__float_as_uint(v) & 0xFFFFFF00u) | cl;
                TOP3_INS_U32(u0, u1, u2, u);
            }
        #pragma unroll
        for (int mask = 16; mask <= 32; mask <<= 1) {
            unsigned int o0 = (unsigned int)__shfl_xor((int)u0, mask);
            unsigned int o1 = (unsigned int)__shfl_xor((int)u1, mask);
            unsigned int o2 = (unsigned int)__shfl_xor((int)u2, mask);
            TOP3_INS_U32(u0, u1, u2, o0);
            TOP3_INS_U32(u0, u1, u2, o1);
            TOP3_INS_U32(u0, u1, u2, o2);
        }
        if (g == 0) {
            int rl = wm * 64 + nr * 16 + q;
            tops[wn][rl][0] = __uint_as_float(u0 & 0xFFFFFF00u) - BIAS;
            tops[wn][rl][1] = __uint_as_float(u1 & 0xFFFFFF00u) - BIAS;
            tops[wn][rl][2] = __uint_as_float(u2 & 0xFFFFFF00u) - BIAS;
        }
    }
    __syncthreads();

    if (tid < BM) {
        float a0v = tops[0][tid][0], a1v = tops[0][tid][1], a2v = tops[0][tid][2];
        TOP3_INSERT(a0v, a1v, a2v, tops[1][tid][0]);
        TOP3_INSERT(a0v, a1v, a2v, tops[1][tid][1]);
        TOP3_INSERT(a0v, a1v, a2v, tops[1][tid][2]);
        float* dst = wsTop + (size_t)(row0 + tid) * 24 + pblock * 3;
        dst[0] = a0v; dst[1] = a1v; dst[2] = a2v;
    }
}

// ---------------------------------------------------------------------------
// Final merge: fold 8 pblocks' top3, add row norm, sqrt + softmin, store.
// ---------------------------------------------------------------------------
__global__ __launch_bounds__(256) void merge_kernel(
        const float* __restrict__ wsTop, const float* __restrict__ fnorm,
        float* __restrict__ out) {
    int r = blockIdx.x * 256 + threadIdx.x;      // 25088 = 98*256 exact
    const float* p = wsTop + (size_t)r * 24;
    float t0 = p[0], t1 = p[1], t2 = p[2];
    #pragma unroll
    for (int pb = 1; pb < 8; ++pb) {
        TOP3_INSERT(t0, t1, t2, p[pb * 3 + 0]);
        TOP3_INSERT(t0, t1, t2, p[pb * 3 + 1]);
        TOP3_INSERT(t0, t1, t2, p[pb * 3 + 2]);
    }
    float fn = fnorm[r];
    float d0 = sqrtf(fmaxf(fn + t0, 0.f));
    float d1 = sqrtf(fmaxf(fn + t1, 0.f));
    float d2 = sqrtf(fmaxf(fn + t2, 0.f));
    float w0 = 1.f / (1.f + __expf(d0 - d1) + __expf(d0 - d2));
    out[r] = w0 * d0;
}

extern "C" void kernel_launch(void* const* d_in, const int* in_sizes, int n_in,
                              void* d_out, int out_size, void* d_ws, size_t ws_size,
                              hipStream_t stream) {
    (void)in_sizes; (void)n_in; (void)out_size; (void)ws_size;
    const float* embeds    = (const float*)d_in[0];   // [8,3136,512] fp32
    const float* centroids = (const float*)d_in[1];   // [1024,512]  fp32
    float* out = (float*)d_out;

    // ws layout (bytes):
    //   cnorm  @ 0         (4 KB)
    //   fnorm  @ 4096      (100,352 B)
    //   wsTop  @ 104448    (25088*8*3*4 = 2,408,448 B)  [row][pblock][3]
    //   EbT    @ 2512896   (25,690,112 B bf16, fragment-tiled)
    //   CbT    @ 28203008  (1,048,576 B bf16, fragment-tiled)  total ~27.9 MB
    char* ws = (char*)d_ws;
    float*          cnorm = (float*)(ws);
    float*          fnorm = (float*)(ws + 4096);
    float*          wsTop = (float*)(ws + 104448);
    unsigned short* EbT   = (unsigned short*)(ws + 2512896);
    unsigned short* CbT   = (unsigned short*)(ws + 28203008);

    tconv_kernel<<<NROW / 32, 256, 0, stream>>>(embeds,    EbT, fnorm, 3, 8);
    tconv_kernel<<<Pp / 32,   256, 0, stream>>>(centroids, CbT, cnorm, 6, 64);
    mfma_topk_kernel<<<NMB_PAD * 8, 256, 0, stream>>>(EbT, CbT, cnorm, wsTop);
    merge_kernel<<<NROW / 256, 256, 0, stream>>>(wsTop, fnorm, out);
}

// Round 12
// 54.581 us; speedup vs baseline: 1.1993x; 1.0610x over previous
//
#include <hip/hip_runtime.h>
#include <math.h>

#define Cc 512
#define Pp 1024
#define NROW 25088      // B*N = 8*3136
#define BM 128          // rows per block
#define BNP 128         // centroid cols per block (8 pblocks)
#define NMB 196         // real mblocks = 25088/128
#define NMB_PAD 200     // padded so mblocks group 8-per-XCD
#define BIAS 4096.f     // makes v = cn+BIAS-2dot strictly positive for packing

typedef short  bf16x8 __attribute__((ext_vector_type(8)));   // 8 bf16 = 4 VGPR
typedef float  f32x4  __attribute__((ext_vector_type(4)));
typedef unsigned short u16x8 __attribute__((ext_vector_type(8)));
typedef unsigned short u16x4 __attribute__((ext_vector_type(4)));

__device__ __forceinline__ unsigned short bf16_rne(float f) {
    unsigned int u = __float_as_uint(f);
    return (unsigned short)((u + 0x7fffu + ((u >> 16) & 1u)) >> 16);
}

// branch-free sorted insert (float), for cross-pblock merges
#define TOP3_INSERT(t0, t1, t2, v)                                  \
    do {                                                            \
        float _n0 = fminf((t0), (v));                               \
        float _h0 = fmaxf((t0), (v));                               \
        float _n1 = fminf((t1), _h0);                               \
        float _h1 = fmaxf((t1), _h0);                               \
        float _n2 = fminf((t2), _h1);                               \
        (t0) = _n0; (t1) = _n1; (t2) = _n2;                         \
    } while (0)

// branch-free sorted insert (packed u32: high-24 float bits | 8-bit col id)
#define TOP3_INS_U32(t0, t1, t2, v)                                 \
    do {                                                            \
        unsigned int _n0 = min((t0), (v));                          \
        unsigned int _h0 = max((t0), (v));                          \
        unsigned int _n1 = min((t1), _h0);                          \
        unsigned int _h1 = max((t1), _h0);                          \
        unsigned int _n2 = min((t2), _h1);                          \
        (t0) = _n0; (t1) = _n1; (t2) = _n2;                         \
    } while (0)

#define GLOAD_LDS16(gp, lp)                                             \
    __builtin_amdgcn_global_load_lds(                                   \
        (const __attribute__((address_space(1))) void*)(const void*)(gp),\
        (__attribute__((address_space(3))) void*)(void*)(lp), 16, 0, 0)

// ---------------------------------------------------------------------------
// Transpose-conv (proven): fp32 -> bf16 RNE, re-tiled into MFMA fragment
// order, fused row squared-norm.
// Tile = 16 rows x 32 k = 64 chunks of 16B; chunk (g,q) at lane l = g*16+q.
// Tile id = rowblk_base + kt*ktstride + nrt, rowblk_base = rb + (rb>>lg)*(15<<lg)
//   A (embeds):    lg=3, ktstride=8   -> [mblock][kstep 16][nrtile 8][64*16B]
//   B (centroids): lg=6, ktstride=64  -> [kstep 16][ptile 64][64*16B]
// ---------------------------------------------------------------------------
__global__ __launch_bounds__(256) void tconv_kernel(
        const float* __restrict__ src, unsigned short* __restrict__ dst,
        float* __restrict__ nrm, int lg, int ktstride) {
    __shared__ unsigned short buf[32 * 512];   // 32 KB
    __shared__ float snorm[32 * 8];            // 1 KB

    const int t = threadIdx.x;
    const size_t R0 = (size_t)blockIdx.x * 32;

    #pragma unroll
    for (int p = 0; p < 16; ++p) {
        int idx = p * 1024 + t * 4;
        float4 v = *(const float4*)(src + R0 * Cc + idx);
        u16x4 o;
        o[0] = bf16_rne(v.x); o[1] = bf16_rne(v.y);
        o[2] = bf16_rne(v.z); o[3] = bf16_rne(v.w);
        *(u16x4*)&buf[idx] = o;
    }
    __syncthreads();

    const int w = t >> 6, g = (t >> 4) & 3, q = t & 15, l = t & 63;
    const int rb = (int)(R0 >> 4);
    const int rowblk_base = rb + (rb >> lg) * (15 << lg);
    float fns = 0.f;
    #pragma unroll
    for (int p = 0; p < 8; ++p) {
        int cg  = p * 4 + w;              // tile-local group 0..31
        int kt  = cg >> 1, nrt = cg & 1;
        int row = nrt * 16 + q;
        u16x8 ch = *(const u16x8*)&buf[row * 512 + kt * 32 + g * 8];
        #pragma unroll
        for (int i = 0; i < 8; ++i) {
            float x = __uint_as_float((unsigned int)(unsigned short)ch[i] << 16);
            fns = fmaf(x, x, fns);
        }
        size_t tile = (size_t)rowblk_base + (size_t)kt * ktstride + nrt;
        *(u16x8*)(dst + tile * 512 + l * 8) = ch;
    }
    snorm[((w & 1) * 16 + q) * 8 + (w >> 1) * 4 + g] = fns;
    __syncthreads();
    if (t < 32) {
        float s = 0.f;
        #pragma unroll
        for (int j = 0; j < 8; ++j) s += snorm[t * 8 + j];
        nrm[R0 + t] = s;
    }
}

// ---------------------------------------------------------------------------
// Main: split-pipe 128x128 MFMA tile, TWO k-steps per barrier (32 MFMA/wave
// between barriers). A fragments direct global->VGPR, prefetched 2 k-steps
// ahead (compiler-counted reg waits). B double-buffered 2x16KB (two
// fragment-ordered 8KB k-panels per buffer, 4 DMA instrs/wave); counted
// vmcnt(8) at step end drains next iter's B, keeps the 8 A loads in flight.
// Fragment reads are contiguous 1KB/wave => conflict-free, no swizzle.
// Swapped-operand MFMA (cents lane-local in C) + packed-u32 top-3.
// Grid: 1600 blocks (200 padded mblocks x 8 pblocks), 256 thr = 4 waves 2x2.
// acc[mc][nr]: cent = p0+wn*64+mc*16+g*4+reg ; row = row0+wm*64+nr*16+q
// ---------------------------------------------------------------------------
__global__ __launch_bounds__(256, 3) void mfma_topk_kernel(
        const unsigned short* __restrict__ EbT, const unsigned short* __restrict__ CbT,
        const float* __restrict__ cnorm, float* __restrict__ wsTop) {
    const int xcd = blockIdx.x & 7;
    const int t8  = blockIdx.x >> 3;          // 0..199
    const int mblock = ((t8 >> 3) << 3) | xcd;
    const int pblock = t8 & 7;
    if (mblock >= NMB) return;                // uniform early-exit

    __shared__ unsigned short Blds[2][16384 / 2];  // 2 x 16 KB (2 k-panels each)
    __shared__ float tops[2][BM][3];               // 3 KB

    const int tid  = threadIdx.x;
    const int lane = tid & 63;
    const int w    = tid >> 6;
    const int wm   = w >> 1;       // 0..1 row half
    const int wn   = w & 1;        // 0..1 cent half
    const int g    = lane >> 4;    // 0..3
    const int q    = lane & 15;    // 0..15
    const int row0 = mblock * BM;
    const int p0   = pblock * BNP;

    f32x4 acc[4][4];               // [mc][nr]
    #pragma unroll
    for (int mc = 0; mc < 4; ++mc)
        #pragma unroll
        for (int nr = 0; nr < 4; ++nr) acc[mc][nr] = (f32x4){0.f, 0.f, 0.f, 0.f};

    // A fragment base (u16): tile=512 u16, tiles [mblock][kt 16][nrt 8]
    const unsigned short* Ab = EbT + ((size_t)mblock * 128 + wm * 4) * 512 + lane * 8;
    // B: tiles [kt 16][ptile 64]; this block's 8 tiles per kt are contiguous
    const unsigned short* Bg = CbT + (size_t)pblock * 8 * 512;

    // stage TWO k-panels (kt = 2i, 2i+1) into buffer buf: 4 DMA instrs/thread
    auto STAGE_B2 = [&](int buf, int i) {
        #pragma unroll
        for (int ks = 0; ks < 2; ++ks) {
            const unsigned short* src = Bg + (size_t)(2 * i + ks) * 32768;
            #pragma unroll
            for (int it = 0; it < 2; ++it) {
                int c = tid + it * 256;
                GLOAD_LDS16(src + c * 8, (char*)Blds[buf] + ks * 8192 + c * 16);
            }
        }
    };

    bf16x8 af[2][2][4];            // [buf][ks][nr] = 64 VGPR
    STAGE_B2(0, 0);                // B iter0 (kt 0,1): 4 DMA
    #pragma unroll
    for (int ks = 0; ks < 2; ++ks)
        #pragma unroll
        for (int nr = 0; nr < 4; ++nr)
            af[0][ks][nr] = *(const bf16x8*)(Ab + (size_t)ks * 4096 + nr * 512);
    // in flight: B0(4 oldest) + A0(8) -> drain B0, keep A0
    asm volatile("s_waitcnt vmcnt(8)" ::: "memory");
    __builtin_amdgcn_s_barrier();

    #pragma unroll
    for (int i = 0; i < 8; ++i) {
        const int cur = i & 1, nxt = cur ^ 1;
        if (i < 7) {
            STAGE_B2(nxt, i + 1);                      // 4 DMA
            #pragma unroll
            for (int ks = 0; ks < 2; ++ks)
                #pragma unroll
                for (int nr = 0; nr < 4; ++nr)
                    af[nxt][ks][nr] = *(const bf16x8*)(
                        Ab + (size_t)(2 * i + 2 + ks) * 4096 + nr * 512);
        }

        #pragma unroll
        for (int ks = 0; ks < 2; ++ks) {
            const char* Bsk = (const char*)Blds[cur] + ks * 8192;
            bf16x8 bc[4];
            #pragma unroll
            for (int mc = 0; mc < 4; ++mc)
                bc[mc] = *(const bf16x8*)(Bsk + (wn * 4 + mc) * 1024 + lane * 16);
            __builtin_amdgcn_s_setprio(1);
            #pragma unroll
            for (int mc = 0; mc < 4; ++mc)
                #pragma unroll
                for (int nr = 0; nr < 4; ++nr)
                    acc[mc][nr] = __builtin_amdgcn_mfma_f32_16x16x32_bf16(
                        bc[mc], af[cur][ks][nr], acc[mc][nr], 0, 0, 0);
            __builtin_amdgcn_s_setprio(0);
        }

        // drain next iter's B(4); keep next iter's A(8) in flight
        if (i < 7) asm volatile("s_waitcnt vmcnt(8)" ::: "memory");
        else       asm volatile("s_waitcnt vmcnt(0)" ::: "memory");
        __builtin_amdgcn_s_barrier();
    }

    // ---- epilogue: cents lane-local; top-3 per row over 64 cents/wave ----
    float cnb[4][4];
    #pragma unroll
    for (int mc = 0; mc < 4; ++mc)
        #pragma unroll
        for (int reg = 0; reg < 4; ++reg)
            cnb[mc][reg] = cnorm[p0 + wn * 64 + mc * 16 + g * 4 + reg] + BIAS;

    #pragma unroll
    for (int nr = 0; nr < 4; ++nr) {
        unsigned int u0 = 0xFFFFFFFFu, u1 = 0xFFFFFFFFu, u2 = 0xFFFFFFFFu;
        #pragma unroll
        for (int mc = 0; mc < 4; ++mc)
            #pragma unroll
            for (int reg = 0; reg < 4; ++reg) {
                float v = fmaf(-2.f, acc[mc][nr][reg], cnb[mc][reg]);  // > 0
                unsigned int cl = (unsigned int)(wn * 64 + mc * 16 + g * 4 + reg);
                unsigned int u = (__float_as_uint(v) & 0xFFFFFF00u) | cl;
                TOP3_INS_U32(u0, u1, u2, u);
            }
        #pragma unroll
        for (int mask = 16; mask <= 32; mask <<= 1) {
            unsigned int o0 = (unsigned int)__shfl_xor((int)u0, mask);
            unsigned int o1 = (unsigned int)__shfl_xor((int)u1, mask);
            unsigned int o2 = (unsigned int)__shfl_xor((int)u2, mask);
            TOP3_INS_U32(u0, u1, u2, o0);
            TOP3_INS_U32(u0, u1, u2, o1);
            TOP3_INS_U32(u0, u1, u2, o2);
        }
        if (g == 0) {
            int rl = wm * 64 + nr * 16 + q;
            tops[wn][rl][0] = __uint_as_float(u0 & 0xFFFFFF00u) - BIAS;
            tops[wn][rl][1] = __uint_as_float(u1 & 0xFFFFFF00u) - BIAS;
            tops[wn][rl][2] = __uint_as_float(u2 & 0xFFFFFF00u) - BIAS;
        }
    }
    __syncthreads();

    if (tid < BM) {
        float a0v = tops[0][tid][0], a1v = tops[0][tid][1], a2v = tops[0][tid][2];
        TOP3_INSERT(a0v, a1v, a2v, tops[1][tid][0]);
        TOP3_INSERT(a0v, a1v, a2v, tops[1][tid][1]);
        TOP3_INSERT(a0v, a1v, a2v, tops[1][tid][2]);
        float* dst = wsTop + (size_t)(row0 + tid) * 24 + pblock * 3;
        dst[0] = a0v; dst[1] = a1v; dst[2] = a2v;
    }
}

// ---------------------------------------------------------------------------
// Final merge: fold 8 pblocks' top3, add row norm, sqrt + softmin, store.
// ---------------------------------------------------------------------------
__global__ __launch_bounds__(256) void merge_kernel(
        const float* __restrict__ wsTop, const float* __restrict__ fnorm,
        float* __restrict__ out) {
    int r = blockIdx.x * 256 + threadIdx.x;      // 25088 = 98*256 exact
    const float* p = wsTop + (size_t)r * 24;
    float t0 = p[0], t1 = p[1], t2 = p[2];
    #pragma unroll
    for (int pb = 1; pb < 8; ++pb) {
        TOP3_INSERT(t0, t1, t2, p[pb * 3 + 0]);
        TOP3_INSERT(t0, t1, t2, p[pb * 3 + 1]);
        TOP3_INSERT(t0, t1, t2, p[pb * 3 + 2]);
    }
    float fn = fnorm[r];
    float d0 = sqrtf(fmaxf(fn + t0, 0.f));
    float d1 = sqrtf(fmaxf(fn + t1, 0.f));
    float d2 = sqrtf(fmaxf(fn + t2, 0.f));
    float w0 = 1.f / (1.f + __expf(d0 - d1) + __expf(d0 - d2));
    out[r] = w0 * d0;
}

extern "C" void kernel_launch(void* const* d_in, const int* in_sizes, int n_in,
                              void* d_out, int out_size, void* d_ws, size_t ws_size,
                              hipStream_t stream) {
    (void)in_sizes; (void)n_in; (void)out_size; (void)ws_size;
    const float* embeds    = (const float*)d_in[0];   // [8,3136,512] fp32
    const float* centroids = (const float*)d_in[1];   // [1024,512]  fp32
    float* out = (float*)d_out;

    // ws layout (bytes):
    //   cnorm  @ 0         (4 KB)
    //   fnorm  @ 4096      (100,352 B)
    //   wsTop  @ 104448    (25088*8*3*4 = 2,408,448 B)  [row][pblock][3]
    //   EbT    @ 2512896   (25,690,112 B bf16, fragment-tiled)
    //   CbT    @ 28203008  (1,048,576 B bf16, fragment-tiled)  total ~27.9 MB
    char* ws = (char*)d_ws;
    float*          cnorm = (float*)(ws);
    float*          fnorm = (float*)(ws + 4096);
    float*          wsTop = (float*)(ws + 104448);
    unsigned short* EbT   = (unsigned short*)(ws + 2512896);
    unsigned short* CbT   = (unsigned short*)(ws + 28203008);

    tconv_kernel<<<NROW / 32, 256, 0, stream>>>(embeds,    EbT, fnorm, 3, 8);
    tconv_kernel<<<Pp / 32,   256, 0, stream>>>(centroids, CbT, cnorm, 6, 64);
    mfma_topk_kernel<<<NMB_PAD * 8, 256, 0, stream>>>(EbT, CbT, cnorm, wsTop);
    merge_kernel<<<NROW / 256, 256, 0, stream>>>(wsTop, fnorm, out);
}